// Round 12
// baseline (262.351 us; speedup 1.0000x reference)
//
#include <hip/hip_runtime.h>

#define B_ROWS 14336
#define D_DIM  512
#define C_CLS  7
#define M_CLS  2048

typedef __attribute__((ext_vector_type(4))) float f32x4;

// fp8 scale: fea*64 -> sigma~3.2 in e4m3 range; Gram scaled by 4096
#define FP8_SCALE 64.0f
#define INV_2S2   (2.0f / 4096.0f)

// K0: fea->fp8 FRAGMENT-PACKED + row norms + logits + BN-stats partials.
// Packed 16B units: flat = g*512 + p*64 + lane, g=row/16, p=k/64, lane=q*16+s.
// 896 blocks x 16 rows (one packed group) -> 4 rows/wave.
// BN stats: per-COLUMN accumulators (r11 bug: was summed across columns).
__global__ __launch_bounds__(256) void k_prep(const float* __restrict__ fea,
                                              const float* __restrict__ W,
                                              char* __restrict__ f8p,
                                              float* __restrict__ an,
                                              float* __restrict__ logits,
                                              float* __restrict__ S1,
                                              float* __restrict__ S2) {
  int t = threadIdx.x, wave = t >> 6, lane = t & 63;
  __shared__ char lrow[16 * 528];  // 16 rows x 512B fp8 (+16 pad)
  __shared__ float sst[4][14];     // per-wave: s1[0..6], s2[7..13]

  int r0 = blockIdx.x * 16;
  float s1c[7], s2c[7];            // lane0-held per-COLUMN partials
#pragma unroll
  for (int c = 0; c < 7; ++c) { s1c[c] = 0.f; s2c[c] = 0.f; }
#pragma unroll
  for (int k = 0; k < 4; ++k) {
    int rl = wave * 4 + k;
    int row = r0 + rl;
    const float4* fr4 = (const float4*)(fea + (size_t)row * D_DIM);
    float4 v0 = fr4[lane * 2], v1 = fr4[lane * 2 + 1];
    float s = v0.x * v0.x + v0.y * v0.y + v0.z * v0.z + v0.w * v0.w +
              v1.x * v1.x + v1.y * v1.y + v1.z * v1.z + v1.w * v1.w;
#pragma unroll
    for (int o = 1; o < 64; o <<= 1) s += __shfl_xor(s, o);
    if (lane == 0) an[row] = s;
    // fp8 e4m3 pack (scaled)
    int w0 = __builtin_amdgcn_cvt_pk_fp8_f32(v0.x * FP8_SCALE, v0.y * FP8_SCALE, 0, 0);
    w0     = __builtin_amdgcn_cvt_pk_fp8_f32(v0.z * FP8_SCALE, v0.w * FP8_SCALE, w0, 1);
    int w1 = __builtin_amdgcn_cvt_pk_fp8_f32(v1.x * FP8_SCALE, v1.y * FP8_SCALE, 0, 0);
    w1     = __builtin_amdgcn_cvt_pk_fp8_f32(v1.z * FP8_SCALE, v1.w * FP8_SCALE, w1, 1);
    *(int2*)&lrow[rl * 528 + lane * 8] = make_int2(w0, w1);
#pragma unroll
    for (int c = 0; c < 7; ++c) {
      const float4* w4 = (const float4*)(W + c * D_DIM);
      float4 q0 = w4[lane * 2], q1 = w4[lane * 2 + 1];
      float p = v0.x * q0.x + v0.y * q0.y + v0.z * q0.z + v0.w * q0.w +
                v1.x * q1.x + v1.y * q1.y + v1.z * q1.z + v1.w * q1.w;
#pragma unroll
      for (int o = 1; o < 64; o <<= 1) p += __shfl_xor(p, o);
      if (lane == 0) {
        logits[row * 7 + c] = p;
        s1c[c] += p;
        s2c[c] += p * p;
      }
    }
  }
  if (lane == 0) {
#pragma unroll
    for (int c = 0; c < 7; ++c) {
      sst[wave][c] = s1c[c];
      sst[wave][7 + c] = s2c[c];
    }
  }
  __syncthreads();
  if (t < 14) {
    float v = sst[0][t] + sst[1][t] + sst[2][t] + sst[3][t];
    if (t < 7) atomicAdd(&S1[t], v);
    else       atomicAdd(&S2[t - 7], v);
  }
  // packed write-out: 512 16B-chunks/block (one group), coalesced
  int4* outp = (int4*)f8p + (size_t)blockIdx.x * 512;
#pragma unroll
  for (int pi = 0; pi < 2; ++pi) {
    int c = pi * 256 + t;
    int p = c >> 6, l = c & 63;
    int q = l >> 4, sIdx = l & 15;
    int2 lo = *(const int2*)&lrow[sIdx * 528 + p * 64 + q * 8];
    int2 hi = *(const int2*)&lrow[sIdx * 528 + p * 64 + 32 + q * 8];
    outp[c] = make_int4(lo.x, lo.y, hi.x, hi.y);
  }
}

// K1: fused Gram + exp reductions, barrier-free register-direct fp8 MFMA.
// 256x256 block tiles, 16 waves (4x4 of 64x64) = 4 waves/SIMD at 128 regs:
// halves unique line traffic per cell AND raises waves/CU to 16 (MLP).
// Grid 738: bid<640 gram (xcd=bid&7; xcd<7,unit<36 self tri; else cross,
// 4 dummy); bid>=640: bnout (98 x 1024 = 100352 exactly).
// rowsum partials row-major [row*32+slot]; all 32 slots provably covered.
__global__ __launch_bounds__(1024) void k_gram(const char* __restrict__ f8p,
                                               const float* __restrict__ an,
                                               const float* __restrict__ logits,
                                               float* __restrict__ S,
                                               float* __restrict__ rs_part,
                                               const float* __restrict__ S1,
                                               const float* __restrict__ S2,
                                               const float* __restrict__ gamma,
                                               const float* __restrict__ beta,
                                               float* __restrict__ out) {
  int bid = blockIdx.x;
  int t = threadIdx.x;
  if (bid >= 640) {  // BN output (S1/S2 finalized by k_prep dispatch)
    int idx = (bid - 640) * 1024 + t;
    int row = idx / 7;
    int c = idx - row * 7;
    float mu = S1[c] * (1.f / 14336.f);
    float var = S2[c] * (1.f / 14336.f) - mu * mu;
    out[idx] = gamma[c] * (logits[idx] - mu) * rsqrtf(var + 1e-5f) + beta[c];
    return;
  }
  int xcd = bid & 7, unit = bid >> 3;
  int lane = t & 63, wave = t >> 6;

  int c1, c2, TI, TJ, Sidx;
  bool self;
  if (xcd < 7 && unit < 36) {
    int tj = 0, t2 = unit;
    while (t2 > tj) { t2 -= (tj + 1); ++tj; }  // idx = tj*(tj+1)/2 + ti, ti<=tj
    TI = t2; TJ = tj;
    c1 = xcd; c2 = xcd; Sidx = xcd; self = true;
  } else {
    int e = (xcd < 7) ? (xcd * 44 + unit - 36) : (308 + unit);
    if (e >= 384) return;  // 4 dummy blocks
    int p = e >> 6;
    int tile = e & 63;
    TJ = tile >> 3; TI = tile & 7;
    c1 = p + 1; c2 = 0; Sidx = 7 + p; self = false;
  }
  bool diag = self && (TI == TJ);
  bool off  = self && (TI < TJ);
  int rowA0 = c1 * M_CLS + TI * 256;
  int rowB0 = c2 * M_CLS + TJ * 256;

  int wr = wave >> 2, wc = wave & 3;  // 4x4 waves of 64x64
  int q = lane >> 4, s = lane & 15;

  // fragment 16B-unit offsets: group g at g*512, + p*64 + lane
  const longlong2* fl = (const longlong2*)f8p;
  int gA = (rowA0 >> 4) + wr * 4;
  int gB = (rowB0 >> 4) + wc * 4;
  int oA[4], oB[4];
#pragma unroll
  for (int m = 0; m < 4; ++m) {
    oA[m] = (gA + m) * 512 + lane;
    oB[m] = (gB + m) * 512 + lane;
  }

  f32x4 acc[4][4];
#pragma unroll
  for (int i = 0; i < 4; ++i)
#pragma unroll
    for (int j = 0; j < 4; ++j)
      acc[i][j] = (f32x4){0.f, 0.f, 0.f, 0.f};

  longlong2 fa[4], fbv[4];
#pragma unroll
  for (int p = 0; p < 8; ++p) {
#pragma unroll
    for (int m = 0; m < 4; ++m) {
      fa[m]  = fl[oA[m] + p * 64];
      fbv[m] = fl[oB[m] + p * 64];
    }
#pragma unroll
    for (int mi = 0; mi < 4; ++mi)
#pragma unroll
      for (int mj = 0; mj < 4; ++mj)
        acc[mi][mj] = __builtin_amdgcn_mfma_f32_16x16x32_fp8_fp8(
            fa[mi].x, fbv[mj].x, acc[mi][mj], 0, 0, 0);
#pragma unroll
    for (int mi = 0; mi < 4; ++mi)
#pragma unroll
      for (int mj = 0; mj < 4; ++mj)
        acc[mi][mj] = __builtin_amdgcn_mfma_f32_16x16x32_fp8_fp8(
            fa[mi].y, fbv[mj].y, acc[mi][mj], 0, 0, 0);
  }

  // row norms into registers (fp32-exact, L2-hot)
  float anA[4][4], anB[4];
#pragma unroll
  for (int mi = 0; mi < 4; ++mi)
#pragma unroll
    for (int rg = 0; rg < 4; ++rg)
      anA[mi][rg] = an[rowA0 + wr * 64 + mi * 16 + q * 4 + rg];
#pragma unroll
  for (int mj = 0; mj < 4; ++mj)
    anB[mj] = an[rowB0 + wc * 64 + mj * 16 + s];

  // Epilogue. C/D layout (16x16x32, dtype-independent): col=lane&15,
  // row=(lane>>4)*4+reg. 5-kernel sum via exp-squaring from e1=exp(-0.05*d2).
  // KDE partials (self only): direct slot TJ*4+wc (rows of band TI),
  // mirror slot TI*4+wr (rows of band TJ) -> 32 slots/row exactly once.
  float blockAcc = 0.f;
  float colAcc[4] = {0.f, 0.f, 0.f, 0.f};
  int slotD = TJ * 4 + wc;
#pragma unroll
  for (int mi = 0; mi < 4; ++mi) {
#pragma unroll
    for (int rg = 0; rg < 4; ++rg) {
      int rl = wr * 64 + mi * 16 + q * 4 + rg;
      float aA = anA[mi][rg];
      float rowAcc = 0.f;
#pragma unroll
      for (int mj = 0; mj < 4; ++mj) {
        int cl = wc * 64 + mj * 16 + s;
        float g = acc[mi][mj][rg];
        float d2 = fmaxf(aA + anB[mj] - g * INV_2S2, 0.f);
        if (diag && rl == cl) d2 = 0.f;  // exact diagonal
        float e1 = __expf(-0.05f * d2);
        float e2 = e1 * e1, e4 = e2 * e2, e8 = e4 * e4, e16 = e8 * e8;
        blockAcc += e1 + e2 + e4 + e8 + e16;
        if (self) {
          float ek = __expf(-12.5f * d2);  // KDE: 1/(2*0.2^2)
          rowAcc += ek;
          if (off) colAcc[mj] += ek;
        }
      }
      if (self) {
        rowAcc += __shfl_xor(rowAcc, 1);
        rowAcc += __shfl_xor(rowAcc, 2);
        rowAcc += __shfl_xor(rowAcc, 4);
        rowAcc += __shfl_xor(rowAcc, 8);
        if (s == 0) rs_part[(size_t)(rowA0 + rl) * 32 + slotD] = rowAcc;
      }
    }
  }
  if (off) {
    int slotM = TI * 4 + wr;
#pragma unroll
    for (int mj = 0; mj < 4; ++mj) {
      float v = colAcc[mj];
      v += __shfl_xor(v, 16);
      v += __shfl_xor(v, 32);
      if (q == 0)
        rs_part[(size_t)(rowB0 + wc * 64 + mj * 16 + s) * 32 + slotM] = v;
    }
    blockAcc *= 2.f;  // mirror tile counted once
  }
#pragma unroll
  for (int o = 1; o < 64; o <<= 1) blockAcc += __shfl_xor(blockAcc, o);
  if (lane == 0) atomicAdd(&S[Sidx], blockAcc);
}

// K2: per-class KDE weight + affinity term (7 blocks). out[100352] pre-zeroed.
__global__ __launch_bounds__(256) void k_final(const float* __restrict__ rs_part,
                                               const float* __restrict__ S,
                                               float* __restrict__ out) {
  int c = blockIdx.x, t = threadIdx.x;
  // log_norm = -256*ln(2*pi*0.04) - ln(2048)
  const float LOG_NORM = 345.9110632f;
  float v = 0.f;
  for (int i = t; i < M_CLS; i += 256) {
    const float4* rp = (const float4*)(rs_part + (size_t)(c * M_CLS + i) * 32);
    float rsum = 0.f;
#pragma unroll
    for (int jj = 0; jj < 8; ++jj) {
      float4 x = rp[jj];
      rsum += x.x + x.y + x.z + x.w;
    }
    v += 1.f / (logf(rsum) + LOG_NORM);
  }
#pragma unroll
  for (int o = 1; o < 64; o <<= 1) v += __shfl_xor(v, o);
  __shared__ float r[4];
  if ((t & 63) == 0) r[t >> 6] = v;
  __syncthreads();
  if (t == 0) {
    float w = 1.f / ((r[0] + r[1] + r[2] + r[3]) + 1e-5f);
    const float inv_m2 = 1.0f / ((float)M_CLS * (float)M_CLS);
    float Ssrc = S[c];
    float Stgt = (c > 0) ? S[0] : S[1];
    float X    = (c > 0) ? S[6 + c] : S[7];  // cross Sidx 7+p is (p+1,0); X01==X10
    float mmd = (Ssrc + Stgt - 2.f * X) * inv_m2;
    atomicAdd(&out[100352], -mmd * w);
  }
}

extern "C" void kernel_launch(void* const* d_in, const int* in_sizes, int n_in,
                              void* d_out, int out_size, void* d_ws, size_t ws_size,
                              hipStream_t stream) {
  const float* fea   = (const float*)d_in[0];
  const float* W_fc  = (const float*)d_in[1];
  const float* gamma = (const float*)d_in[2];
  const float* beta  = (const float*)d_in[3];
  float* out = (float*)d_out;

  char* ws = (char*)d_ws;
  char* f8p = ws;                                // packed fp8 fea: 7,340,032 B
  float* fbase   = (float*)(ws + 7340032);
  float* an      = fbase;                        // 14336
  float* logits  = fbase + 14336;                // 100352
  float* zb      = fbase + 114688;               // 64-float zero block
  float* S1      = zb;                           //   [0..6]
  float* S2      = zb + 7;                       //   [7..13]
  float* S       = zb + 16;                      //   [16..28] (13 used)
  float* rs_part = fbase + 114752;               // 14336*32 row-major (fully written)

  hipMemsetAsync(zb, 0, 64 * sizeof(float), stream);
  hipMemsetAsync(out + 100352, 0, sizeof(float), stream);
  k_prep <<<896, 256,  0, stream>>>(fea, W_fc, f8p, an, logits, S1, S2);
  k_gram <<<738, 1024, 0, stream>>>(f8p, an, logits, S, rs_part, S1, S2,
                                    gamma, beta, out);
  k_final<<<7,   256,  0, stream>>>(rs_part, S, out);
}

// Round 13
// 245.800 us; speedup vs baseline: 1.0673x; 1.0673x over previous
//
#include <hip/hip_runtime.h>

#define B_ROWS 14336
#define D_DIM  512
#define C_CLS  7
#define M_CLS  2048

typedef __attribute__((ext_vector_type(4))) float f32x4;

// fp8 scale: fea*64 -> sigma~3.2 in e4m3 range; Gram scaled by 4096
#define FP8_SCALE 64.0f
#define INV_2S2   (2.0f / 4096.0f)

typedef const __attribute__((address_space(1))) char gchar_t;
typedef __attribute__((address_space(3))) char lchar_t;

__device__ __forceinline__ void gload16(const char* g, char* l) {
  // async global->LDS DMA, 16B/lane, dest = wave-uniform base + lane*16
  __builtin_amdgcn_global_load_lds((gchar_t*)g, (lchar_t*)l, 16, 0, 0);
}

// K0: fea->fp8 packed in the k_gram LDS IMAGE + row norms + logits + zero zb.
// f8p layout: [group g = row/16][kt = k/64][lane l]16B, where the 16B at
// (g,kt,l) with s=l>>2, phys chunk pc=l&3, logical chunk c=pc^(s&3) holds
// row (16g+s) bytes {kt*64+c*8 ..+7} and {kt*64+32+c*8 ..+7}.
// So k_gram's DMA is identity (coalesced) and its ds_read_b128 at phys chunk
// q^(s&3) retrieves logical chunk q = the two K-32 fp8 operands (.x=lo,.y=hi).
__global__ __launch_bounds__(256) void k_prep(const float* __restrict__ fea,
                                              const float* __restrict__ W,
                                              char* __restrict__ f8p,
                                              float* __restrict__ an,
                                              float* __restrict__ logits,
                                              float* __restrict__ zb) {  // 64 floats
  int t = threadIdx.x, wave = t >> 6, lane = t & 63;
  if (blockIdx.x == 0 && t < 64) zb[t] = 0.f;
  __shared__ char lrow[16 * 528];  // 16 rows x 512B fp8 (+16 pad)

  int r0 = blockIdx.x * 16;
#pragma unroll
  for (int k = 0; k < 4; ++k) {
    int rl = wave * 4 + k;
    int row = r0 + rl;
    const float4* fr4 = (const float4*)(fea + (size_t)row * D_DIM);
    float4 v0 = fr4[lane * 2], v1 = fr4[lane * 2 + 1];
    float s = v0.x * v0.x + v0.y * v0.y + v0.z * v0.z + v0.w * v0.w +
              v1.x * v1.x + v1.y * v1.y + v1.z * v1.z + v1.w * v1.w;
#pragma unroll
    for (int o = 1; o < 64; o <<= 1) s += __shfl_xor(s, o);
    if (lane == 0) an[row] = s;
    int w0 = __builtin_amdgcn_cvt_pk_fp8_f32(v0.x * FP8_SCALE, v0.y * FP8_SCALE, 0, 0);
    w0     = __builtin_amdgcn_cvt_pk_fp8_f32(v0.z * FP8_SCALE, v0.w * FP8_SCALE, w0, 1);
    int w1 = __builtin_amdgcn_cvt_pk_fp8_f32(v1.x * FP8_SCALE, v1.y * FP8_SCALE, 0, 0);
    w1     = __builtin_amdgcn_cvt_pk_fp8_f32(v1.z * FP8_SCALE, v1.w * FP8_SCALE, w1, 1);
    *(int2*)&lrow[rl * 528 + lane * 8] = make_int2(w0, w1);
#pragma unroll
    for (int c = 0; c < 7; ++c) {
      const float4* w4 = (const float4*)(W + c * D_DIM);
      float4 q0 = w4[lane * 2], q1 = w4[lane * 2 + 1];
      float p = v0.x * q0.x + v0.y * q0.y + v0.z * q0.z + v0.w * q0.w +
                v1.x * q1.x + v1.y * q1.y + v1.z * q1.z + v1.w * q1.w;
#pragma unroll
      for (int o = 1; o < 64; o <<= 1) p += __shfl_xor(p, o);
      if (lane == 0) logits[row * 7 + c] = p;
    }
  }
  __syncthreads();
  // image write-out: 512 16B chunks/block, coalesced
  int4* outp = (int4*)f8p + (size_t)blockIdx.x * 512;
#pragma unroll
  for (int pi = 0; pi < 2; ++pi) {
    int idx = pi * 256 + t;
    int kt = idx >> 6, l = idx & 63;
    int s = l >> 2, pc = l & 3;
    int c = pc ^ (s & 3);
    int2 lo = *(const int2*)&lrow[s * 528 + kt * 64 + c * 8];
    int2 hi = *(const int2*)&lrow[s * 528 + kt * 64 + 32 + c * 8];
    outp[idx] = make_int4(lo.x, lo.y, hi.x, hi.y);
  }
}

// K1: fused Gram + exp reductions. 256x128 tiles, 8 waves (4x2 of 64x64),
// BK=64, LDS-SHARED ping-pong DMA staging (each byte enters the CU once:
// 244 MB total vs 637 MB register-direct), 1 barrier/kt, 2 blocks/CU
// (__launch_bounds__(512,4), LDS 48KB) so barrier drains interleave.
// Grid 1328 = 166 units x 8 xcd: unit<72 & xcd<7: self (class=xcd, macro
// tri-enum, 2 half-tiles); unit<159: cross; unit>=159: BN-stats (56).
// rowsum partials row-major [row*32+slot]: direct slot j*2+wc, mirror i*4+wr
// (covers all 32 slots exactly once; no zeroing).
__global__ __launch_bounds__(512, 4) void k_gram(const char* __restrict__ f8p,
                                                 const float* __restrict__ an,
                                                 const float* __restrict__ logits,
                                                 float* __restrict__ S,
                                                 float* __restrict__ rs_part,
                                                 float* __restrict__ S1,
                                                 float* __restrict__ S2,
                                                 float* __restrict__ aff) {
  int unit = blockIdx.x >> 3, xcd = blockIdx.x & 7;
  int t = threadIdx.x, lane = t & 63, wave = t >> 6;
  if (blockIdx.x == 0 && t == 0) aff[0] = 0.f;

  if (unit >= 159) {  // batch-norm stats partials (zb zeroed by k_prep)
    int sidx = (unit - 159) * 8 + xcd;  // 0..55
    int c = sidx >> 3, chunk = sidx & 7;
    int r0 = chunk * 1792;
    float s1 = 0.f, s2 = 0.f;
    for (int j = t; j < 1792; j += 512) {
      float v = logits[(r0 + j) * 7 + c];
      s1 += v;
      s2 += v * v;
    }
#pragma unroll
    for (int o = 1; o < 64; o <<= 1) {
      s1 += __shfl_xor(s1, o);
      s2 += __shfl_xor(s2, o);
    }
    __shared__ float r1_[8], r2_[8];
    if (lane == 0) { r1_[wave] = s1; r2_[wave] = s2; }
    __syncthreads();
    if (t == 0) {
      float a = 0.f, b = 0.f;
#pragma unroll
      for (int w = 0; w < 8; ++w) { a += r1_[w]; b += r2_[w]; }
      atomicAdd(&S1[c], a);
      atomicAdd(&S2[c], b);
    }
    return;
  }

  int c1, c2, TI, J16, Sidx;   // TI: 256-row band; J16: 128-col band
  bool self, dup2;
  if (xcd < 7 && unit < 72) {
    int m = unit >> 1, h = unit & 1;
    int Jm = 0, t2 = m;
    while (t2 > Jm) { t2 -= (Jm + 1); ++Jm; }  // m = Jm*(Jm+1)/2 + i, i<=Jm
    TI = t2; J16 = Jm * 2 + h;
    c1 = xcd; c2 = xcd; Sidx = xcd; self = true;
    dup2 = (Jm > TI);
  } else {
    int e = (xcd < 7) ? (xcd * 87 + unit - 72) : (609 + unit);
    int p = e >> 7;
    int tl = e & 127;
    TI = tl >> 4; J16 = tl & 15;
    c1 = p + 1; c2 = 0; Sidx = 7 + p; self = false;
    dup2 = false;
  }
  int rowA0 = c1 * M_CLS + TI * 256;
  int rowB0 = c2 * M_CLS + J16 * 128;

  // LDS: [buf][A 16KB | B 8KB]
  __shared__ char lds[2][24576];

  int wr = wave >> 1, wc = wave & 1;  // 4x2 waves of 64x64
  int q = lane >> 4, s = lane & 15;
  int gAbase = rowA0 >> 4, gBbase = rowB0 >> 4;

#define STAGE(kt_, b_)                                                          \
  do {                                                                          \
    int ga = wave * 2;                                                          \
    gload16(f8p + ((size_t)(gAbase + ga) * 8 + (kt_)) * 1024 + lane * 16,       \
            &lds[b_][ga * 1024 + lane * 16]);                                   \
    gload16(f8p + ((size_t)(gAbase + ga + 1) * 8 + (kt_)) * 1024 + lane * 16,   \
            &lds[b_][(ga + 1) * 1024 + lane * 16]);                             \
    gload16(f8p + ((size_t)(gBbase + wave) * 8 + (kt_)) * 1024 + lane * 16,     \
            &lds[b_][16384 + wave * 1024 + lane * 16]);                         \
  } while (0)

  f32x4 acc[4][4];
#pragma unroll
  for (int i = 0; i < 4; ++i)
#pragma unroll
    for (int j = 0; j < 4; ++j)
      acc[i][j] = (f32x4){0.f, 0.f, 0.f, 0.f};

  int fragOff = s * 64 + ((q ^ (s & 3)) * 16);  // swizzled b128 addr in group

  STAGE(0, 0);
  for (int kt = 0; kt < 8; ++kt) {
    int b = kt & 1;
    __syncthreads();            // drains buf b's DMA (a full compute phase old)
    if (kt < 7) STAGE(kt + 1, b ^ 1);
    const char* A  = lds[b];
    const char* Bp = lds[b] + 16384;
    longlong2 fa[4], fbv[4];
#pragma unroll
    for (int mi = 0; mi < 4; ++mi)
      fa[mi] = *(const longlong2*)&A[(wr * 4 + mi) * 1024 + fragOff];
#pragma unroll
    for (int mj = 0; mj < 4; ++mj)
      fbv[mj] = *(const longlong2*)&Bp[(wc * 4 + mj) * 1024 + fragOff];
#pragma unroll
    for (int mi = 0; mi < 4; ++mi)
#pragma unroll
      for (int mj = 0; mj < 4; ++mj)
        acc[mi][mj] = __builtin_amdgcn_mfma_f32_16x16x32_fp8_fp8(
            fa[mi].x, fbv[mj].x, acc[mi][mj], 0, 0, 0);
#pragma unroll
    for (int mi = 0; mi < 4; ++mi)
#pragma unroll
      for (int mj = 0; mj < 4; ++mj)
        acc[mi][mj] = __builtin_amdgcn_mfma_f32_16x16x32_fp8_fp8(
            fa[mi].y, fbv[mj].y, acc[mi][mj], 0, 0, 0);
  }
#undef STAGE

  // row norms into registers (fp32-exact, L2-hot)
  float anA[4][4], anB[4];
#pragma unroll
  for (int mi = 0; mi < 4; ++mi)
#pragma unroll
    for (int rg = 0; rg < 4; ++rg)
      anA[mi][rg] = an[rowA0 + wr * 64 + mi * 16 + q * 4 + rg];
#pragma unroll
  for (int mj = 0; mj < 4; ++mj)
    anB[mj] = an[rowB0 + wc * 64 + mj * 16 + s];

  // Epilogue. C/D layout (16x16x32, dtype-independent): col=lane&15,
  // row=(lane>>4)*4+reg. 5-kernel sum via exp-squaring from e1=exp(-0.05*d2).
  float blockAcc = 0.f;
  float colAcc[4] = {0.f, 0.f, 0.f, 0.f};
  int slotD = J16 * 2 + wc;
#pragma unroll
  for (int mi = 0; mi < 4; ++mi) {
#pragma unroll
    for (int rg = 0; rg < 4; ++rg) {
      int rl = wr * 64 + mi * 16 + q * 4 + rg;
      float aA = anA[mi][rg];
      float rowAcc = 0.f;
#pragma unroll
      for (int mj = 0; mj < 4; ++mj) {
        int cl = wc * 64 + mj * 16 + s;
        float g = acc[mi][mj][rg];
        float d2 = fmaxf(aA + anB[mj] - g * INV_2S2, 0.f);
        if (self && (rowA0 + rl) == (rowB0 + cl)) d2 = 0.f;  // exact diagonal
        float e1 = __expf(-0.05f * d2);
        float e2 = e1 * e1, e4 = e2 * e2, e8 = e4 * e4, e16 = e8 * e8;
        blockAcc += e1 + e2 + e4 + e8 + e16;
        if (self) {
          float ek = __expf(-12.5f * d2);  // KDE: 1/(2*0.2^2)
          rowAcc += ek;
          if (dup2) colAcc[mj] += ek;
        }
      }
      if (self) {
        rowAcc += __shfl_xor(rowAcc, 1);
        rowAcc += __shfl_xor(rowAcc, 2);
        rowAcc += __shfl_xor(rowAcc, 4);
        rowAcc += __shfl_xor(rowAcc, 8);
        if (s == 0) rs_part[(size_t)(rowA0 + rl) * 32 + slotD] = rowAcc;
      }
    }
  }
  if (dup2) {
    int slotM = TI * 4 + wr;
#pragma unroll
    for (int mj = 0; mj < 4; ++mj) {
      float v = colAcc[mj];
      v += __shfl_xor(v, 16);
      v += __shfl_xor(v, 32);
      if (q == 0)
        rs_part[(size_t)(rowB0 + wc * 64 + mj * 16 + s) * 32 + slotM] = v;
    }
    blockAcc *= 2.f;  // mirror macro counted once
  }
#pragma unroll
  for (int o = 1; o < 64; o <<= 1) blockAcc += __shfl_xor(blockAcc, o);
  if (lane == 0) atomicAdd(&S[Sidx], blockAcc);
}

// K2: bnout (blocks 0..391) + per-class KDE weight & affinity term (392..398).
// aff zeroed in k_gram.
__global__ __launch_bounds__(256) void k_final(const float* __restrict__ logits,
                                               const float* __restrict__ S1,
                                               const float* __restrict__ S2,
                                               const float* __restrict__ gamma,
                                               const float* __restrict__ beta,
                                               const float* __restrict__ rs_part,
                                               const float* __restrict__ S,
                                               float* __restrict__ out) {
  int b = blockIdx.x, t = threadIdx.x;
  if (b < 392) {
    int idx = b * 256 + t;  // 392*256 = 100352 exactly
    int row = idx / 7;
    int c = idx - row * 7;
    float mu = S1[c] * (1.f / 14336.f);
    float var = S2[c] * (1.f / 14336.f) - mu * mu;
    out[idx] = gamma[c] * (logits[idx] - mu) * rsqrtf(var + 1e-5f) + beta[c];
    return;
  }
  int c = b - 392;
  // log_norm = -256*ln(2*pi*0.04) - ln(2048)
  const float LOG_NORM = 345.9110632f;
  float v = 0.f;
  for (int i = t; i < M_CLS; i += 256) {
    const float4* rp = (const float4*)(rs_part + (size_t)(c * M_CLS + i) * 32);
    float rsum = 0.f;
#pragma unroll
    for (int jj = 0; jj < 8; ++jj) {
      float4 x = rp[jj];
      rsum += x.x + x.y + x.z + x.w;
    }
    v += 1.f / (logf(rsum) + LOG_NORM);
  }
#pragma unroll
  for (int o = 1; o < 64; o <<= 1) v += __shfl_xor(v, o);
  __shared__ float r[4];
  if ((t & 63) == 0) r[t >> 6] = v;
  __syncthreads();
  if (t == 0) {
    float w = 1.f / ((r[0] + r[1] + r[2] + r[3]) + 1e-5f);
    const float inv_m2 = 1.0f / ((float)M_CLS * (float)M_CLS);
    float Ssrc = S[c];
    float Stgt = (c > 0) ? S[0] : S[1];
    float X    = (c > 0) ? S[6 + c] : S[7];  // cross Sidx 7+p is (p+1,0); X01==X10
    float mmd = (Ssrc + Stgt - 2.f * X) * inv_m2;
    atomicAdd(&out[100352], -mmd * w);
  }
}

extern "C" void kernel_launch(void* const* d_in, const int* in_sizes, int n_in,
                              void* d_out, int out_size, void* d_ws, size_t ws_size,
                              hipStream_t stream) {
  const float* fea   = (const float*)d_in[0];
  const float* W_fc  = (const float*)d_in[1];
  const float* gamma = (const float*)d_in[2];
  const float* beta  = (const float*)d_in[3];
  float* out = (float*)d_out;

  char* ws = (char*)d_ws;
  char* f8p = ws;                                // packed fp8 image: 7,340,032 B
  float* fbase   = (float*)(ws + 7340032);
  float* an      = fbase;                        // 14336
  float* logits  = fbase + 14336;                // 100352
  float* zb      = fbase + 114688;               // 64-float zero block
  float* S1      = zb;                           //   [0..6]
  float* S2      = zb + 7;                       //   [7..13]
  float* S       = zb + 16;                      //   [16..28] (13 used)
  float* rs_part = fbase + 114752;               // 14336*32 row-major (fully written)

  k_prep <<<896,  256, 0, stream>>>(fea, W_fc, f8p, an, logits, zb);
  k_gram <<<1328, 512, 0, stream>>>(f8p, an, logits, S, rs_part, S1, S2,
                                    out + 100352);
  k_final<<<399,  256, 0, stream>>>(logits, S1, S2, gamma, beta, rs_part, S, out);
}